// Round 9
// baseline (287.112 us; speedup 1.0000x reference)
//
#include <hip/hip_runtime.h>

// SPGG Q-learning step on a 2048x2048 torus — SINGLE fused kernel, v8
// ("regflow-2": 2 horizontal cells/thread, <=64 VGPR forced, XCD swizzle).
//
// v7 post-mortem (107 us): swizzle fixed traffic (FETCH 181->66 MB, best of
// all rounds) but time didn't move: occupancy 27%, VALU 17%, hbm 20% ->
// latency-bound at starved occupancy. VGPR=68 is just past the 64-VGPR
// cliff (waves/CU halve at vgpr={64,128,256} [m69]) -> 16 waves/CU cap.
// Regflow's compute is the cheapest of the series (~18 us VALU issue, zero
// LDS); it only lacks latency-hiding waves.
//
// v8 = regflow under the cliff:
//   - 2 cells/thread: halves per-thread live state (32-cell tt window,
//     18 b-values, 8 profits, 2x qr/qn) -> fits 64 VGPR;
//   - __launch_bounds__(256, 8): force allocator to 64 VGPR = 8 waves/SIMD;
//   - neighbor gathers issue AFTER the profit computation (out of the
//     register-pressure peak; 8 waves/SIMD hide their latency via TLP);
//   - same bijective XCD swizzle (8192 blocks: (b&7)*1024 + b>>3 -> one
//     contiguous 256-row band per XCD, tt band 2 MB < 4 MB private L2).
//
// Numerics: identical per-cell op sequence as the passing v1-v7 (int-exact
// coop sums; __f*_rn ops in the reference's exact order; exp in double,
// rounded once).

#define LSIDE 2048
#define LMASK 2047
#define LSHIFT 11
#define NCELL (LSIDE * LSIDE)

__global__ __launch_bounds__(256, 8) void spgg_fused(
    const int* __restrict__ tmin,   // type_t_minus
    const int* __restrict__ tt,     // type_t
    const float* __restrict__ Q,    // Q_tensor [N,4]
    const int* __restrict__ ldir,   // learning_direction
    const float* __restrict__ lp,   // learning_probabilities
    float* __restrict__ Qn,         // out: Q_new [N,4]
    float* __restrict__ prof,       // out: profit [N]
    float* __restrict__ t1out)      // out: type_t1 [N]
{
    const int t = threadIdx.x;
    // XCD-contiguous bijective swizzle: 8192 blocks, 8 XCDs, 1024 blocks/XCD.
    const int blk = ((blockIdx.x & 7) << 10) + (blockIdx.x >> 3);
    const int i   = blk >> 2;                       // 4 blocks per lattice row
    const int j0  = ((blk & 3) << 9) + (t << 1);    // 2-cell group start col
    const int idx0 = (i << LSHIFT) + j0;

    // ---- 1. per-cell vector loads ----
    const int2   dir2 = *(const int2*)&ldir[idx0];
    const float2 lp2  = *(const float2*)&lp[idx0];
    const int2   A2   = *(const int2*)&tmin[idx0];
    const float4 qr0  = ((const float4*)Q)[idx0 + 0];
    const float4 qr1  = ((const float4*)Q)[idx0 + 1];

    // ---- 2. tt window (rows i-3..i+3) into registers, int2 loads ----
    int rowoff[7];
    #pragma unroll
    for (int r = 0; r < 7; ++r) rowoff[r] = ((i + r - 3) & LMASK) << LSHIFT;
    const int cm4 = (j0 - 4) & LMASK;
    const int cm2 = (j0 - 2) & LMASK;
    const int cp2 = (j0 + 2) & LMASK;
    const int cp4 = (j0 + 4) & LMASK;

    const int2 Lm3  = *(const int2*)&tt[rowoff[0] + j0];   // cols 0..1
    const int2 Lm2a = *(const int2*)&tt[rowoff[1] + cm2];  // -2..-1
    const int2 Lm2b = *(const int2*)&tt[rowoff[1] + j0];   //  0..1
    const int2 Lm2c = *(const int2*)&tt[rowoff[1] + cp2];  //  2..3
    const int2 Lm1a = *(const int2*)&tt[rowoff[2] + cm2];
    const int2 Lm1b = *(const int2*)&tt[rowoff[2] + j0];
    const int2 Lm1c = *(const int2*)&tt[rowoff[2] + cp2];
    const int2 L0a  = *(const int2*)&tt[rowoff[3] + cm4];  // -4..-3
    const int2 L0b  = *(const int2*)&tt[rowoff[3] + cm2];
    const int2 L0c  = *(const int2*)&tt[rowoff[3] + j0];
    const int2 L0d  = *(const int2*)&tt[rowoff[3] + cp2];
    const int2 L0e  = *(const int2*)&tt[rowoff[3] + cp4];  //  4..5
    const int2 Lp1a = *(const int2*)&tt[rowoff[4] + cm2];
    const int2 Lp1b = *(const int2*)&tt[rowoff[4] + j0];
    const int2 Lp1c = *(const int2*)&tt[rowoff[4] + cp2];
    const int2 Lp2a = *(const int2*)&tt[rowoff[5] + cm2];
    const int2 Lp2b = *(const int2*)&tt[rowoff[5] + j0];
    const int2 Lp2c = *(const int2*)&tt[rowoff[5] + cp2];
    const int2 Lp3  = *(const int2*)&tt[rowoff[6] + j0];

    // ---- 3. unpack (constant indices -> registers) ----
    // Maps: t_m3[x]=col x; t_m2/t_m1/t_p1/t_p2[x]=col x-2; t_0[x]=col x-4;
    //       t_p3[x]=col x. (cols relative to j0)
    int t_m3[2], t_m2[6], t_m1[6], t_0[10], t_p1[6], t_p2[6], t_p3[2];
    t_m3[0]=Lm3.x;  t_m3[1]=Lm3.y;
    t_m2[0]=Lm2a.x; t_m2[1]=Lm2a.y; t_m2[2]=Lm2b.x;
    t_m2[3]=Lm2b.y; t_m2[4]=Lm2c.x; t_m2[5]=Lm2c.y;
    t_m1[0]=Lm1a.x; t_m1[1]=Lm1a.y; t_m1[2]=Lm1b.x;
    t_m1[3]=Lm1b.y; t_m1[4]=Lm1c.x; t_m1[5]=Lm1c.y;
    t_0[0]=L0a.x;  t_0[1]=L0a.y;  t_0[2]=L0b.x;  t_0[3]=L0b.y;
    t_0[4]=L0c.x;  t_0[5]=L0c.y;  t_0[6]=L0d.x;  t_0[7]=L0d.y;
    t_0[8]=L0e.x;  t_0[9]=L0e.y;
    t_p1[0]=Lp1a.x; t_p1[1]=Lp1a.y; t_p1[2]=Lp1b.x;
    t_p1[3]=Lp1b.y; t_p1[4]=Lp1c.x; t_p1[5]=Lp1c.y;
    t_p2[0]=Lp2a.x; t_p2[1]=Lp2a.y; t_p2[2]=Lp2b.x;
    t_p2[3]=Lp2b.y; t_p2[4]=Lp2c.x; t_p2[5]=Lp2c.y;
    t_p3[0]=Lp3.x;  t_p3[1]=Lp3.y;

    const float KB        = 0.5554f;  // float32(R / 5.0)
    const float ETA       = 0.8f;
    const float ONE_M_ETA = 0.2f;     // float32(1.0 - 0.8)
    const float GAMMA     = 0.8f;

    // ---- 4. b grid: b = (float)(5-point int sum) * KB (int adds exact) ----
    // b_m2[c] c=0..1; b_m1[ci] c=ci-1; b_0[ci] c=ci-2; b_p1[ci] c=ci-1;
    // b_p2[c] c=0..1.
    float b_m2[2], b_m1[4], b_0[6], b_p1[4], b_p2[2];
    #pragma unroll
    for (int c = 0; c < 2; ++c) {
        int cn = t_m2[c+2] + t_m3[c] + t_m1[c+2] + t_m2[c+1] + t_m2[c+3];
        b_m2[c] = __fmul_rn((float)cn, KB);
    }
    #pragma unroll
    for (int ci = 0; ci < 4; ++ci) {   // c = ci-1
        int cn = t_m1[ci+1] + t_m2[ci+1] + t_0[ci+3] + t_m1[ci] + t_m1[ci+2];
        b_m1[ci] = __fmul_rn((float)cn, KB);
    }
    #pragma unroll
    for (int ci = 0; ci < 6; ++ci) {   // c = ci-2
        int cn = t_0[ci+2] + t_m1[ci] + t_p1[ci] + t_0[ci+1] + t_0[ci+3];
        b_0[ci] = __fmul_rn((float)cn, KB);
    }
    #pragma unroll
    for (int ci = 0; ci < 4; ++ci) {   // c = ci-1
        int cn = t_p1[ci+1] + t_0[ci+3] + t_p2[ci+1] + t_p1[ci] + t_p1[ci+2];
        b_p1[ci] = __fmul_rn((float)cn, KB);
    }
    #pragma unroll
    for (int c = 0; c < 2; ++c) {
        int cn = t_p2[c+2] + t_p1[c+2] + t_p3[c] + t_p2[c+1] + t_p2[c+3];
        b_p2[c] = __fmul_rn((float)cn, KB);
    }

    // profit from 5 b's — reference's exact op order:
    // plus_sum order (c, up, down, left, right); s1 subtracts 1.0 per term.
    auto profit5 = [&](float b_c, float b_u, float b_d, float b_l, float b_r,
                       int coop) -> float {
        float s0 = __fadd_rn(__fadd_rn(__fadd_rn(__fadd_rn(b_c, b_u), b_d), b_l), b_r);
        float s1 = __fadd_rn(__fadd_rn(__fadd_rn(__fadd_rn(
                       __fsub_rn(b_c, 1.0f), __fsub_rn(b_u, 1.0f)),
                       __fsub_rn(b_d, 1.0f)), __fsub_rn(b_l, 1.0f)),
                       __fsub_rn(b_r, 1.0f));
        return coop ? s1 : s0;
    };

    // ---- 5. candidate profits: row i cols -1..2, rows i+-1 cols 0..1 ----
    float P0[4], Pm1[2], Pp1[2];
    #pragma unroll
    for (int ci = 0; ci < 4; ++ci)     // c = ci-1
        P0[ci] = profit5(b_0[ci+1], b_m1[ci], b_p1[ci], b_0[ci], b_0[ci+2],
                         t_0[ci+3]);
    #pragma unroll
    for (int c = 0; c < 2; ++c)
        Pm1[c] = profit5(b_m1[c+1], b_m2[c], b_0[c+2], b_m1[c], b_m1[c+2],
                         t_m1[c+2]);
    #pragma unroll
    for (int c = 0; c < 2; ++c)
        Pp1[c] = profit5(b_p1[c+1], b_0[c+2], b_p2[c], b_p1[c], b_p1[c+2],
                         t_p1[c+2]);

    // Q-learning update value — exact reference op order.
    auto upd_of = [&](float profit, float4 q4, int Ai, int Bi) -> float {
        float q0 = (Bi == 0) ? q4.x : q4.z;
        float q1 = (Bi == 0) ? q4.y : q4.w;
        float mx = fmaxf(q0, q1);
        int k = Ai * 2 + Bi;
        float old = (k == 0) ? q4.x : ((k == 1) ? q4.y : ((k == 2) ? q4.z : q4.w));
        float t0 = __fmul_rn(GAMMA, mx);
        float t1 = __fadd_rn(profit, t0);
        float t2 = __fmul_rn(ETA, t1);
        float t3 = __fmul_rn(ONE_M_ETA, old);
        return __fadd_rn(t3, t2);
    };

    // ---- 6. own cells: upd + Q/prof stores ----
    int   B[2];
    float updv[2];
    #pragma unroll
    for (int k = 0; k < 2; ++k) {
        B[k] = t_0[k + 4];
        int    Ak = (k == 0) ? A2.x : A2.y;
        float4 qk = (k == 0) ? qr0 : qr1;
        updv[k] = upd_of(P0[k + 1], qk, Ak, B[k]);
        int kk = Ak * 2 + B[k];
        float4 qo;
        qo.x = (kk == 0) ? updv[k] : qk.x;
        qo.y = (kk == 1) ? updv[k] : qk.y;
        qo.z = (kk == 2) ? updv[k] : qk.z;
        qo.w = (kk == 3) ? updv[k] : qk.w;
        ((float4*)Qn)[idx0 + k] = qo;
    }
    float2 pr2; pr2.x = P0[1]; pr2.y = P0[2];
    *(float2*)&prof[idx0] = pr2;

    // ---- 7. gathers (after pressure peak; TLP hides latency) ----
    int An[2];
    float4 qn4[2];
    int dirk[2]; dirk[0] = dir2.x; dirk[1] = dir2.y;
    #pragma unroll
    for (int k = 0; k < 2; ++k) {
        // dir: 0=left(j-1) 1=right(j+1) 2=up(i-1) 3=down(i+1)
        int di = (dirk[k] == 3) - (dirk[k] == 2);
        int dj = (dirk[k] == 1) - (dirk[k] == 0);
        int nidx = (((i + di) & LMASK) << LSHIFT) + ((j0 + k + dj) & LMASK);
        qn4[k] = ((const float4*)Q)[nidx];
        An[k]  = tmin[nidx];
    }

    // ---- 8. fermi: select neighbor profit/type from registers ----
    float e2[2];
    int   Bn[2];
    #pragma unroll
    for (int k = 0; k < 2; ++k) {
        int dir = dirk[k];
        float Pn = (dir == 0) ? P0[k]       // left  (i, k-1)
                 : (dir == 1) ? P0[k + 2]   // right (i, k+1)
                 : (dir == 2) ? Pm1[k]      // up    (i-1, k)
                 :              Pp1[k];     // down  (i+1, k)
        Bn[k] = (dir == 0) ? t_0[k + 3]
              : (dir == 1) ? t_0[k + 5]
              : (dir == 2) ? t_m1[k + 2]
              :              t_p1[k + 2];
        float upd_nb = upd_of(Pn, qn4[k], An[k], Bn[k]);
        float e1 = __fsub_rn(updv[k], upd_nb);
        e2[k] = __fmul_rn(e1, 2.0f);        // / K_FERMI(0.5) exactly
    }
    float selv[2];
    #pragma unroll
    for (int k = 0; k < 2; ++k) {
        float ex = (float)exp((double)e2[k]);   // same as passing rounds
        float W  = __fdiv_rn(1.0f, __fadd_rn(1.0f, ex));
        float pvk = (k == 0) ? lp2.x : lp2.y;
        int sel = (pvk <= W) ? Bn[k] : B[k];
        selv[k] = (float)sel;
    }
    float2 t12; t12.x = selv[0]; t12.y = selv[1];
    *(float2*)&t1out[idx0] = t12;
}

extern "C" void kernel_launch(void* const* d_in, const int* in_sizes, int n_in,
                              void* d_out, int out_size, void* d_ws, size_t ws_size,
                              hipStream_t stream) {
    const int*   type_t_minus = (const int*)d_in[0];
    const int*   type_t       = (const int*)d_in[1];
    const float* Q_tensor     = (const float*)d_in[2];
    const int*   ldir         = (const int*)d_in[3];
    const float* lprob        = (const float*)d_in[4];

    float* out   = (float*)d_out;
    float* Qn    = out;                       // [N*4]
    float* t1out = out + (size_t)4 * NCELL;   // [N]
    float* prof  = out + (size_t)5 * NCELL;   // [N]

    const int threads = 256;
    const int blocks  = NCELL / (threads * 2);  // 8192 (4 blocks per row)
    spgg_fused<<<blocks, threads, 0, stream>>>(type_t_minus, type_t, Q_tensor,
                                               ldir, lprob, Qn, prof, t1out);
}